// Round 10
// baseline (328.371 us; speedup 1.0000x reference)
//
#include <hip/hip_runtime.h>
#include <hip/hip_bf16.h>

// TransformerEncLayer on MI355X (gfx950). B=2, M=2048, d=1024, H=16, DK=64, FF=4096.
// Tokens = 4096. LN grids = 4096.
// R24: attn occupancy via pl reuse (evidence: attn sole top-5 @52.2us, occ
//  31.6%, LDS-capped at 4 blocks/CU; R18 inverse experiment showed -1 block =
//  +11% -> TLP-bound). Restructure tile loop to QK(f)->pl->PV(f) per f half,
//  reusing ONE pl buffer (per-wave private; DS ops in-order within wave;
//  lgkmcnt(0) between store/read phases kept). LDS 34.8->25.6KB -> 6
//  blocks/CU (+50% waves). Cost: K/V fragments re-read per f (+16 ds_read
//  /tile/wave, conflict-free). Barrier protocol per tile UNCHANGED (the
//  R18/R20 failure modes don't apply).
// Base: R23/R22 (gemm_bt256 interleave split, verified -7us), R21 (G13
//  vectorized LN/prep/transpose_v), R19 (fused prep), R17 (256^2 engine),
//  R16 (BK=64 ff2 + swizzle), R15 (attn swizzle/XCD/setprio), R14, R13.

typedef __bf16 bf16;
typedef __attribute__((ext_vector_type(8))) __bf16 bf16x8;
typedef __attribute__((ext_vector_type(4))) __bf16 bf16x4;
typedef __attribute__((ext_vector_type(4))) float f32x4;

#define MFMA16(a, b, c) __builtin_amdgcn_mfma_f32_16x16x32_bf16(a, b, c, 0, 0, 0)

__device__ __forceinline__ void ld_g2l16(void* lds, const void* g) {
  __builtin_amdgcn_global_load_lds((const __attribute__((address_space(1))) void*)g,
                                   (__attribute__((address_space(3))) void*)lds,
                                   16, 0, 0);
}

// ---------------------------------------------------------------------------
// dtype detector (flag=1 -> fp32 inputs)
// ---------------------------------------------------------------------------
__global__ __launch_bounds__(256) void detect_dtype(const void* __restrict__ x,
                                                    int* __restrict__ flag) {
  const unsigned short* u = (const unsigned short*)x;
  int cnt = 0;
  for (int i = threadIdx.x; i < 4096; i += 256) {
    const int e = (u[i] >> 7) & 0xFF;
    if (e >= 140) ++cnt;
  }
  __shared__ int sh[256];
  sh[threadIdx.x] = cnt;
  __syncthreads();
  for (int s = 128; s > 0; s >>= 1) {
    if (threadIdx.x < s) sh[threadIdx.x] += sh[threadIdx.x + s];
    __syncthreads();
  }
  if (threadIdx.x == 0) *flag = (sh[0] > 100) ? 1 : 0;
}

__device__ __forceinline__ bf16 load_any(const void* p, size_t i, int fl) {
  return fl ? (bf16)((const float*)p)[i] : ((const bf16*)p)[i];
}

// ---------------------------------------------------------------------------
// Fused preprocessing (R21): one 1D grid, range-decoded block roles.
//  [0,4096):      convert_x (vectorized: float4 in / bf16x4 out)
//  [4096,4112):   convert_small (9 vectors -> packed sm)
//  [4112,5648):   Wq/Wk/Wv 1024^2 -> WqkvT    (64x32-in tiles, 16B stores)
//  [5648,7696):   W1 [1024][4096] -> W1T      (same scheme)
//  [7696,9744):   W2 [4096][1024] -> W2T      (same scheme)
// ---------------------------------------------------------------------------
__global__ __launch_bounds__(256) void prep_kernel(
    const void* __restrict__ x,  bf16* __restrict__ xc,
    const void* p0, const void* p1, const void* p2, const void* p3,
    const void* p4, const void* p5, const void* p6, const void* p7,
    const void* p8, bf16* __restrict__ sm,
    const void* __restrict__ Wq, const void* __restrict__ Wk,
    const void* __restrict__ Wv, bf16* __restrict__ WqkvT,
    const void* __restrict__ W1, bf16* __restrict__ W1T,
    const void* __restrict__ W2, bf16* __restrict__ W2T,
    const int* __restrict__ flag) {
  const int fl = *flag;
  const int Lb = blockIdx.x;
  const int tid = threadIdx.x;
  __shared__ bf16 t[32][72];

  if (Lb < 4096) {                       // convert_x, 1024 elems/block
    const size_t i0 = (size_t)Lb * 1024 + tid * 4;
    bf16x4 v;
    if (fl) {
      const f32x4 f = *(const f32x4*)((const float*)x + i0);
#pragma unroll
      for (int i = 0; i < 4; ++i) v[i] = (bf16)f[i];
    } else {
      v = *(const bf16x4*)((const bf16*)x + i0);
    }
    *(bf16x4*)(xc + i0) = v;
    return;
  }
  if (Lb < 4112) {                       // convert_small
    const int tt = (Lb - 4096) * 256 + tid;  // 0..4095
    const void* ps[9] = {p0, p1, p2, p3, p4, p5, p6, p7, p8};
    const int sz[9]  = {1024, 1024, 1024, 4096, 1024, 1024, 1024, 1024, 1024};
    const int off[9] = {0, 1024, 2048, 3072, 7168, 8192, 9216, 10240, 11264};
#pragma unroll
    for (int a = 0; a < 9; ++a)
      if (tt < sz[a]) sm[off[a] + tt] = load_any(ps[a], tt, fl);
    return;
  }

  // transpose sections
  const void* in;
  bf16* out;
  int R, C, r0, c0;
  if (Lb < 5648) {                       // Wq/Wk/Wv: 1024x1024 each
    const int b2 = Lb - 4112;            // 0..1535
    const int z = b2 >> 9;               // /512
    const int rem = b2 & 511;
    in = (z == 0) ? Wq : (z == 1) ? Wk : Wv;
    out = WqkvT + (size_t)z * 1024 * 1024;
    R = 1024; C = 1024;
    r0 = (rem >> 5) * 64; c0 = (rem & 31) * 32;
  } else if (Lb < 7696) {                // W1: [1024][4096]
    const int b3 = Lb - 5648;            // 0..2047
    in = W1; out = W1T; R = 1024; C = 4096;
    r0 = (b3 >> 7) * 64; c0 = (b3 & 127) * 32;
  } else {                               // W2: [4096][1024]
    const int b4 = Lb - 7696;            // 0..2047
    in = W2; out = W2T; R = 4096; C = 1024;
    r0 = (b4 >> 5) * 64; c0 = (b4 & 31) * 32;
  }
  {
    const int c = tid & 31, rr = tid >> 5;
#pragma unroll
    for (int i = 0; i < 8; ++i) {
      const int r = i * 8 + rr;
      t[c][r] = load_any(in, (size_t)(r0 + r) * C + c0 + c, fl);
    }
    __syncthreads();
    const int d = tid >> 3, ms = tid & 7;
    *(bf16x8*)&out[(size_t)(c0 + d) * R + r0 + ms * 8] = *(const bf16x8*)&t[d][ms * 8];
  }
}

// ---------------------------------------------------------------------------
// V transpose per head from fused qkvb: qkvb[4096][3072] (v at col 2048+)
// -> vT[b*16+h][64][2048]. 64m x 32d tiles, bf16x8 coalesced stores.
// ---------------------------------------------------------------------------
__global__ __launch_bounds__(256) void transpose_v(const bf16* __restrict__ qkvb,
                                                   bf16* __restrict__ vT) {
  __shared__ bf16 t[32][72];
  const int bh = blockIdx.z;
  const int b = bh >> 4, h = bh & 15;
  const int m0 = blockIdx.x * 64, d0 = blockIdx.y * 32;
  const int tid = threadIdx.x;
  const int c = tid & 31, rr = tid >> 5;
#pragma unroll
  for (int i = 0; i < 8; ++i) {
    const int m = i * 8 + rr;
    t[c][m] = qkvb[(size_t)(b * 2048 + m0 + m) * 3072 + 2048 + h * 64 + d0 + c];
  }
  __syncthreads();
  const int d = tid >> 3, ms = tid & 7;
  *(bf16x8*)&vT[((size_t)bh * 64 + d0 + d) * 2048 + m0 + ms * 8] =
      *(const bf16x8*)&t[d][ms * 8];
}

// ---------------------------------------------------------------------------
// 256x256 counted-vmcnt bt-GEMM, R22 interleaved schedule. BK=64, 8 waves.
// (unchanged from R23 -- verified)
// ---------------------------------------------------------------------------
__global__ __launch_bounds__(512, 2) void gemm_bt256(const bf16* __restrict__ A,
                                                     const bf16* __restrict__ BT,
                                                     const bf16* __restrict__ bias,
                                                     bf16* __restrict__ C,
                                                     int M, int N, int K, int relu) {
  __shared__ bf16 sA[2][256 * 64];   // 32KB per buf
  __shared__ bf16 sB[2][256 * 64];
  const int tid = threadIdx.x;
  const int w = tid >> 6, lane = tid & 63;
  const int wm = w >> 2, wn = w & 3;          // 2 x 4 wave grid
  const int m16 = lane & 15, kg = lane >> 4;
  // XCD-aware decode
  const int gx = N >> 8;
  const int L = blockIdx.x;
  const int x8 = L & 7, t1 = L >> 3;
  const int cb = t1 % gx, rb = (t1 / gx) * 8 + x8;
  const int bm = rb * 256, bn = cb * 256;
  const int strow = lane >> 3;                       // row within wave's 8
  const int sslot = ((lane & 7) ^ strow) * 8;        // swizzled source col
  const int s0 = (kg ^ (m16 & 7)) * 8;
  const int s1 = ((kg + 4) ^ (m16 & 7)) * 8;

#define STG_A(p, k0, n)                                                     \
  ld_g2l16(&sA[p][(n) * 4096 + w * 512],                                    \
           A + (size_t)(bm + (n) * 64 + w * 8 + strow) * K + (k0) + sslot)
#define STG_B(p, k0, n)                                                     \
  ld_g2l16(&sB[p][(n) * 4096 + w * 512],                                    \
           BT + (size_t)(bn + (n) * 64 + w * 8 + strow) * K + (k0) + sslot)

  f32x4 acc[8][4];
#pragma unroll
  for (int i = 0; i < 8; ++i)
#pragma unroll
    for (int j = 0; j < 4; ++j) acc[i][j] = (f32x4){0.f, 0.f, 0.f, 0.f};

  // prologue: tile 0 full (8 loads), tile 1 partial A{0,2}+B (6 loads)
  STG_A(0, 0, 0); STG_A(0, 0, 1); STG_A(0, 0, 2); STG_A(0, 0, 3);
  STG_B(0, 0, 0); STG_B(0, 0, 1); STG_B(0, 0, 2); STG_B(0, 0, 3);
  STG_A(1, 64, 0); STG_A(1, 64, 2);
  STG_B(1, 64, 0); STG_B(1, 64, 1); STG_B(1, 64, 2); STG_B(1, 64, 3);

  const int NT = K >> 6;
  for (int t = 0; t < NT; ++t) {
    const int p = t & 1;
    // leftover stage of tile t+1 (A stripes {1,3}, buf p^1): readers of those
    // regions (prev iter phase-2 frags) drained at prev iter's mid-barrier.
    if (t + 1 < NT) {
      STG_A(p ^ 1, (t + 1) * 64, 1);
      STG_A(p ^ 1, (t + 1) * 64, 3);
    }
    if (t < NT - 1)
      __asm__ __volatile__("s_waitcnt vmcnt(8)" ::: "memory");
    else
      __asm__ __volatile__("s_waitcnt vmcnt(0)" ::: "memory");
    __builtin_amdgcn_s_barrier();   // tile t fully landed, all waves

    const bf16* pA = &sA[p][(wm * 128 + m16) * 64];
    const bf16* pB = &sB[p][(wn * 64 + m16) * 64];
    bf16x8 bfr[4][2], af[4][2], af2[4][2];
#pragma unroll
    for (int nf = 0; nf < 4; ++nf) {
      bfr[nf][0] = *(const bf16x8*)(pB + nf * 1024 + s0);
      bfr[nf][1] = *(const bf16x8*)(pB + nf * 1024 + s1);
    }
#pragma unroll
    for (int mf = 0; mf < 4; ++mf) {
      af[mf][0] = *(const bf16x8*)(pA + mf * 1024 + s0);
      af[mf][1] = *(const bf16x8*)(pA + mf * 1024 + s1);
    }
    __builtin_amdgcn_sched_barrier(0);   // pin group boundary for lgkmcnt(8)
#pragma unroll
    for (int mf = 0; mf < 4; ++mf) {
      af2[mf][0] = *(const bf16x8*)(pA + (mf + 4) * 1024 + s0);
      af2[mf][1] = *(const bf16x8*)(pA + (mf + 4) * 1024 + s1);
    }
    __asm__ __volatile__("s_waitcnt lgkmcnt(8)" ::: "memory");  // first 16 done
    __builtin_amdgcn_sched_barrier(0);
    __builtin_amdgcn_s_setprio(1);
#pragma unroll
    for (int mf = 0; mf < 4; ++mf)
#pragma unroll
      for (int nf = 0; nf < 4; ++nf) {
        acc[mf][nf] = MFMA16(af[mf][0], bfr[nf][0], acc[mf][nf]);
        acc[mf][nf] = MFMA16(af[mf][1], bfr[nf][1], acc[mf][nf]);
      }
    __builtin_amdgcn_s_setprio(0);
    __asm__ __volatile__("s_waitcnt lgkmcnt(0)" ::: "memory");  // all 24 done
    __builtin_amdgcn_s_barrier();   // all waves' reads of buf p drained
    __builtin_amdgcn_sched_barrier(0);

    // stage tile t+2 (buf p): A stripes {0,2} + all B -- regions read only by
    // phase-1 frags, drained at the barrier above.
    if (t + 2 < NT) {
      const int k2 = (t + 2) * 64;
      STG_A(p, k2, 0); STG_A(p, k2, 2);
      STG_B(p, k2, 0); STG_B(p, k2, 1); STG_B(p, k2, 2); STG_B(p, k2, 3);
    }

    __builtin_amdgcn_s_setprio(1);
#pragma unroll
    for (int mf = 0; mf < 4; ++mf)
#pragma unroll
      for (int nf = 0; nf < 4; ++nf) {
        acc[mf + 4][nf] = MFMA16(af2[mf][0], bfr[nf][0], acc[mf + 4][nf]);
        acc[mf + 4][nf] = MFMA16(af2[mf][1], bfr[nf][1], acc[mf + 4][nf]);
      }
    __builtin_amdgcn_s_setprio(0);
  }
#undef STG_A
#undef STG_B

  const int r0 = bm + wm * 128, c0 = bn + wn * 64;
#pragma unroll
  for (int nf = 0; nf < 4; ++nf) {
    const int col = c0 + nf * 16 + m16;
    const float bv = (float)bias[col];
#pragma unroll
    for (int mf = 0; mf < 8; ++mf) {
#pragma unroll
      for (int r = 0; r < 4; ++r) {
        const int row = r0 + mf * 16 + kg * 4 + r;
        float v = acc[mf][nf][r] + bv;
        if (relu) v = fmaxf(v, 0.f);
        C[(size_t)row * N + col] = (bf16)v;
      }
    }
  }
}

// ---------------------------------------------------------------------------
// Split-K bt-GEMM 128x64, BK=64, XCD-swizzled 1D grid (1024 blocks).
// (R16 state -- single-buffer + __syncthreads; 24KB LDS keeps 6 blocks/CU.)
// ---------------------------------------------------------------------------
__global__ __launch_bounds__(256) void gemm_bt64_sk(const bf16* __restrict__ A,
                                                    const bf16* __restrict__ BT,
                                                    bf16* __restrict__ C0,
                                                    bf16* __restrict__ C1,
                                                    int M, int N, int Kf, int Kp) {
  __shared__ bf16 sA[2][128 * 32];   // [k-half][row][32]
  __shared__ bf16 sB[2][64 * 32];
  const int tid = threadIdx.x;
  const int wave = tid >> 6, lane = tid & 63;
  const int L = blockIdx.x;
  const int x8 = L & 7;
  const int t1 = L >> 3;
  const int cb = t1 & 15;
  const int u = t1 >> 4;
  const int z = u & 1;
  const int rb = (u >> 1) * 8 + x8;
  const int bm = rb * 128, bn = cb * 64;
  const int kbase = z * Kp;
  const int m16 = lane & 15, kg = lane >> 4;
  const int srow = lane >> 2;
  const int sswz = ((lane & 3) ^ ((srow >> 1) & 3)) * 8;
  const int kswz = (kg ^ ((m16 >> 1) & 3)) * 8;

  f32x4 acc[2][4];
#pragma unroll
  for (int i = 0; i < 2; ++i)
#pragma unroll
    for (int j = 0; j < 4; ++j) acc[i][j] = (f32x4){0.f, 0.f, 0.f, 0.f};

  for (int k0 = 0; k0 < Kp; k0 += 64) {
#pragma unroll
    for (int i = 0; i < 2; ++i) {
      const int c = wave * 2 + i;          // A row chunk 0..7
      const int row = bm + c * 16 + srow;
#pragma unroll
      for (int h = 0; h < 2; ++h)
        ld_g2l16(&sA[h][c * 512], A + (size_t)row * Kf + kbase + k0 + h * 32 + sswz);
    }
    {
      const int row = bn + wave * 16 + srow;  // B row chunk = wave
#pragma unroll
      for (int h = 0; h < 2; ++h)
        ld_g2l16(&sB[h][wave * 512], BT + (size_t)row * Kf + kbase + k0 + h * 32 + sswz);
    }
    __syncthreads();

#pragma unroll
    for (int ks = 0; ks < 2; ++ks) {
      bf16x8 af[2], bfr[4];
#pragma unroll
      for (int t = 0; t < 2; ++t)
        af[t] = *(const bf16x8*)&sA[ks][(wave * 32 + t * 16 + m16) * 32 + kswz];
#pragma unroll
      for (int t = 0; t < 4; ++t)
        bfr[t] = *(const bf16x8*)&sB[ks][(t * 16 + m16) * 32 + kswz];
#pragma unroll
      for (int mt = 0; mt < 2; ++mt)
#pragma unroll
        for (int nt = 0; nt < 4; ++nt)
          acc[mt][nt] = MFMA16(af[mt], bfr[nt], acc[mt][nt]);
    }
    __syncthreads();
  }

  bf16* C = z ? C1 : C0;
  const int r0 = bm + wave * 32;
#pragma unroll
  for (int nt = 0; nt < 4; ++nt) {
    const int col = bn + nt * 16 + m16;
#pragma unroll
    for (int mt = 0; mt < 2; ++mt) {
#pragma unroll
      for (int r = 0; r < 4; ++r) {
        const int row = r0 + mt * 16 + kg * 4 + r;
        C[(size_t)row * N + col] = (bf16)acc[mt][nt][r];
      }
    }
  }
}

// ---------------------------------------------------------------------------
// Staged flash attention, split-KV x2. 1D grid, 1024 blocks.
// R24: per-f pipeline QK(f)->pl->PV(f), SINGLE pl buffer reused across f.
//  pl is per-wave private; DS ops issue in order within a wave, and the
//  lgkmcnt(0) between QK stores and PV reads is kept per f -- so f=1's
//  stores cannot corrupt f=0's reads. LDS 34.8->25.6KB -> 6 blocks/CU.
//  K/V fragments re-read per f (conflict-free via kswz).
// XCD decode: combo c=(z*16+h); all 16 q-tiles of a combo share L%8.
// sK/sV slot-swizzle (slot ^= (row>>1)&3) source + read. exp2-domain softmax.
// Unnormalized bf16 o partials + f32 den partials; combined in ln1.
// ---------------------------------------------------------------------------
__global__ __launch_bounds__(256) void attn_kernel(const bf16* __restrict__ qkvb,
                                                   const bf16* __restrict__ vT,
                                                   bf16* __restrict__ op0,
                                                   bf16* __restrict__ op1,
                                                   float* __restrict__ den0,
                                                   float* __restrict__ den1) {
  __shared__ bf16 sK[2][64 * 32];      // 8 KB
  __shared__ bf16 sV[2][64 * 32];      // 8 KB
  __shared__ bf16 pl[4][16 * 72];      // 9 KB (single buffer, reused per f)
  const int L = blockIdx.x;
  const int x8 = L & 7;
  const int t1 = L >> 3;
  const int qt = t1 & 15;
  const int c  = (t1 >> 4) * 8 + x8;   // combo 0..63
  const int h  = c & 15;
  const int z  = c >> 4;               // 0..3
  const int b = z >> 1, kh = z & 1;
  const int tid = threadIdx.x, wv = tid >> 6, lane = tid & 63;
  const int m16 = lane & 15, kg = lane >> 4;
  const int srow = lane >> 2;
  const int sswz = ((lane & 3) ^ ((srow >> 1) & 3)) * 8;
  const int kswz = (kg ^ ((m16 >> 1) & 3)) * 8;

  const float qs = 1.4426950408889634f / 1024.0f;
  bf16x8 fq0[2], fq1[2];
#pragma unroll
  for (int f = 0; f < 2; ++f) {
    const int q0 = qt * 128 + f * 64 + wv * 16;
    const bf16* qp = qkvb + (size_t)(b * 2048 + q0 + m16) * 3072 + h * 64;
    bf16x8 a = *(const bf16x8*)(qp + kg * 8);
    bf16x8 cc = *(const bf16x8*)(qp + 32 + kg * 8);
#pragma unroll
    for (int i = 0; i < 8; ++i) {
      a[i] = (bf16)((float)a[i] * qs);
      cc[i] = (bf16)((float)cc[i] * qs);
    }
    fq0[f] = a;
    fq1[f] = cc;
  }

  bf16x8 ones;
#pragma unroll
  for (int i = 0; i < 8; ++i) ones[i] = (bf16)1.0f;

  f32x4 o[2][4], oden[2];
#pragma unroll
  for (int f = 0; f < 2; ++f) {
#pragma unroll
    for (int cl = 0; cl < 4; ++cl) o[f][cl] = (f32x4){0.f, 0.f, 0.f, 0.f};
    oden[f] = (f32x4){0.f, 0.f, 0.f, 0.f};
  }

  const bf16* kbase = qkvb + (size_t)(b * 2048) * 3072 + 1024 + h * 64;
  const bf16* vbase = vT + (size_t)(b * 16 + h) * 64 * 2048;
  bf16* plw = &pl[wv][0];

  const int tstart = kh * 1024;
  for (int t0 = tstart; t0 < tstart + 1024; t0 += 64) {
    {
      const int row = wv * 16 + srow;
      ld_g2l16(&sK[0][wv * 512], kbase + (size_t)(t0 + row) * 3072 + sswz);
      ld_g2l16(&sK[1][wv * 512], kbase + (size_t)(t0 + row) * 3072 + 32 + sswz);
      ld_g2l16(&sV[0][wv * 512], vbase + (size_t)row * 2048 + t0 + sswz);
      ld_g2l16(&sV[1][wv * 512], vbase + (size_t)row * 2048 + t0 + 32 + sswz);
    }
    __syncthreads();

#pragma unroll
    for (int f = 0; f < 2; ++f) {
      // QK^T (f half): S'^T[t][q] in exp2 domain -> P into pl
      __builtin_amdgcn_s_setprio(1);
#pragma unroll
      for (int g = 0; g < 4; ++g) {
        const bf16x8 af0 = *(const bf16x8*)&sK[0][(g * 16 + m16) * 32 + kswz];
        const bf16x8 af1 = *(const bf16x8*)&sK[1][(g * 16 + m16) * 32 + kswz];
        f32x4 zz = (f32x4){0.f, 0.f, 0.f, 0.f};
        zz = MFMA16(af0, f ? fq0[1] : fq0[0], zz);
        zz = MFMA16(af1, f ? fq1[1] : fq1[0], zz);
        bf16x4 pv4;
#pragma unroll
        for (int r = 0; r < 4; ++r)
          pv4[r] = (bf16)__builtin_amdgcn_exp2f(zz[r]);
        *(bf16x4*)(plw + m16 * 72 + g * 16 + kg * 4) = pv4;
      }
      __builtin_amdgcn_s_setprio(0);
      __asm__ __volatile__("s_waitcnt lgkmcnt(0)" ::: "memory");

      // PV (f half): pa from pl, fv from sV
      __builtin_amdgcn_s_setprio(1);
#pragma unroll
      for (int tt = 0; tt < 2; ++tt) {
        const bf16x8 pa = *(const bf16x8*)(plw + m16 * 72 + tt * 32 + kg * 8);
        oden[f] = MFMA16(pa, ones, oden[f]);
#pragma unroll
        for (int cl = 0; cl < 4; ++cl) {
          const bf16x8 fv = *(const bf16x8*)&sV[tt][(cl * 16 + m16) * 32 + kswz];
          o[f][cl] = MFMA16(pa, fv, o[f][cl]);
        }
      }
      __builtin_amdgcn_s_setprio(0);
      // f=1's pl stores are DS ops issued after f=0's pl reads (in-order
      // within wave) -- no extra wait needed before reuse.
    }
    __syncthreads();
  }

  bf16* op = kh ? op1 : op0;
  float* dptr = kh ? den1 : den0;
#pragma unroll
  for (int f = 0; f < 2; ++f)
#pragma unroll
    for (int r = 0; r < 4; ++r) {
      const int row = qt * 128 + f * 64 + wv * 16 + kg * 4 + r;
      if (m16 == 0) dptr[((b * 16 + h) << 11) + row] = oden[f][r];
      bf16* opp = op + (size_t)(b * 2048 + row) * 1024 + h * 64;
#pragma unroll
      for (int cl = 0; cl < 4; ++cl) opp[cl * 16 + m16] = (bf16)o[f][cl][r];
    }
}

// ---------------------------------------------------------------------------
// LN1 + attention combine (bf16x4 vectorized).
// attn = (op0+op1)/(den0+den1); h1b = bf16( LN(x + attn)*g1 + be1 ).
// op1 aliases h1b: reads precede the barrier, writes follow; same-thread cover.
// ---------------------------------------------------------------------------
__global__ __launch_bounds__(256) void ln1_kernel(const bf16* __restrict__ x,
                                                  const bf16* __restrict__ op0,
                                                  const bf16* __restrict__ op1,
                                                  const float* __restrict__ den0,
                                                  const float* __restrict__ den1,
                                                  const bf16* __restrict__ g,
                                                  const bf16* __restrict__ be,
                                                  bf16* __restrict__ h1b) {
  const int row = blockIdx.x;           // b*2048 + q
  const int b = row >> 11, q = row & 2047;
  const size_t base = (size_t)row * 1024;
  const int t = threadIdx.x;
  const int h = t >> 4;                 // head of this thread's 4 columns
  const float rden = 1.0f / (den0[((b * 16 + h) << 11) + q] +
                             den1[((b * 16 + h) << 11) + q]);
  const bf16x4 vo0 = *(const bf16x4*)&op0[base + t * 4];
  const bf16x4 vo1 = *(const bf16x4*)&op1[base + t * 4];
  const bf16x4 vx  = *(const bf16x4*)&x[base + t * 4];
  float v[4], s = 0.f, ss = 0.f;
#pragma unroll
  for (int i = 0; i < 4; ++i) {
    const float at = ((float)vo0[i] + (float)vo1[i]) * rden;
    const float xv = (float)vx[i] + at;
    v[i] = xv; s += xv; ss += xv * xv;
  }
#pragma unroll
  for (int m = 1; m < 64; m <<= 1) { s += __shfl_xor(s, m); ss += __shfl_xor(ss, m); }
  __shared__ float rs[4], rss[4];
  const int wave = t >> 6, lane = t & 63;
  if (lane == 0) { rs[wave] = s; rss[wave] = ss; }
  __syncthreads();
  s = rs[0] + rs[1] + rs[2] + rs[3];
  ss = rss[0] + rss[1] + rss[2] + rss[3];
  const float mu = s * (1.f / 1024.f);
  const float var = fmaxf(ss * (1.f / 1024.f) - mu * mu, 0.f);
  const float rstd = rsqrtf(var + 1e-5f);
  const bf16x4 vg  = *(const bf16x4*)&g[t * 4];
  const bf16x4 vbe = *(const bf16x4*)&be[t * 4];
  bf16x4 vout;
#pragma unroll
  for (int i = 0; i < 4; ++i)
    vout[i] = (bf16)((v[i] - mu) * rstd * (float)vg[i] + (float)vbe[i]);
  *(bf16x4*)&h1b[base + t * 4] = vout;
}

// LN2 (vectorized): out = LN(h1b + p0 + p1 + b2)*g2 + be2. grid = 4096.
__global__ __launch_bounds__(256) void ln2_kernel(const bf16* __restrict__ h1b,
                                                  const bf16* __restrict__ p0,
                                                  const bf16* __restrict__ p1,
                                                  const bf16* __restrict__ b2,
                                                  const bf16* __restrict__ g,
                                                  const bf16* __restrict__ be,
                                                  void* __restrict__ out,
                                                  const int* __restrict__ flag) {
  const int fl = *flag;
  const int row = blockIdx.x;
  const size_t base = (size_t)row * 1024;
  const int t = threadIdx.x;
  const bf16x4 vh = *(const bf16x4*)&h1b[base + t * 4];
  const bf16x4 v0 = *(const bf16x4*)&p0[base + t * 4];
  const bf16x4 v1 = *(const bf16x4*)&p1[base + t * 4];
  const bf16x4 vb2 = *(const bf16x4*)&b2[t * 4];
  float v[4], s = 0.f, ss = 0.f;
#pragma unroll
  for (int i = 0; i < 4; ++i) {
    const float xv = (float)vh[i] + (float)v0[i] + (float)v1[i] + (float)vb2[i];
    v[i] = xv; s += xv; ss += xv * xv;
  }
#pragma unroll
  for (int m = 1; m < 64; m <<= 1) { s += __shfl_xor(s, m); ss += __shfl_xor(ss, m); }
  __shared__ float rs[4], rss[4];
  const int wave = t >> 6, lane = t & 63;
  if (lane == 0) { rs[wave] = s; rss[wave] = ss; }
  __syncthreads();
  s = rs[0] + rs[1] + rs[2] + rs[3];
  ss = rss[0] + rss[1] + rss[2] + rss[3];
  const float mu = s * (1.f / 1024.f);
  const float var = fmaxf(ss * (1.f / 1024.f) - mu * mu, 0.f);
  const float rstd = rsqrtf(var + 1e-5f);
  const bf16x4 vg  = *(const bf16x4*)&g[t * 4];
  const bf16x4 vbe = *(const bf16x4*)&be[t * 4];
  if (fl) {
    f32x4 vout;
#pragma unroll
    for (int i = 0; i < 4; ++i)
      vout[i] = (v[i] - mu) * rstd * (float)vg[i] + (float)vbe[i];
    *(f32x4*)((float*)out + base + t * 4) = vout;
  } else {
    bf16x4 vout;
#pragma unroll
    for (int i = 0; i < 4; ++i)
      vout[i] = (bf16)((v[i] - mu) * rstd * (float)vg[i] + (float)vbe[i]);
    *(bf16x4*)((bf16*)out + base + t * 4) = vout;
  }
}

// ---------------------------------------------------------------------------
extern "C" void kernel_launch(void* const* d_in, const int* in_sizes, int n_in,
                              void* d_out, int out_size, void* d_ws, size_t ws_size,
                              hipStream_t stream) {
  const void* x   = d_in[0];
  const void* Wq  = d_in[2];
  const void* bq  = d_in[3];
  const void* Wk  = d_in[4];
  const void* bk  = d_in[5];
  const void* Wv  = d_in[6];
  const void* bv  = d_in[7];
  const void* W1  = d_in[8];
  const void* b1  = d_in[9];
  const void* W2  = d_in[10];
  const void* b2  = d_in[11];
  const void* g1  = d_in[12];
  const void* be1 = d_in[13];
  const void* g2  = d_in[14];
  const void* be2 = d_in[15];

  const size_t MB = 1u << 20;
  char* w = (char*)d_ws;
  int*  flag = (int*)w;                       // 4 B
  bf16* sm   = (bf16*)(w + 65536);            // packed small vectors (~24 KB)
  bf16* bqkvc = sm + 0;        // 3072
  bf16* b1c   = sm + 3072;     // 4096
  bf16* b2c   = sm + 7168;     // 1024
  bf16* g1c   = sm + 8192;
  bf16* be1c  = sm + 9216;
  bf16* g2c   = sm + 10240;
  bf16* be2c  = sm + 11264;
  float* den0 = (float*)(w + 512 * 1024);   // [32][2048] f32 256 KB
  float* den1 = (float*)(w + 768 * 1024);   //            256 KB
  bf16* xc    = (bf16*)(w + 1 * MB);    // [4096][1024]    8 MB (dead after ln1)
  bf16* WqkvT = (bf16*)(w + 9 * MB);    // [3072][1024]    6 MB
  bf16* W1T   = (bf16*)(w + 15 * MB);   // [4096][1024]    8 MB
  bf16* W2T   = (bf16*)(w + 23 * MB);   // [1024][4096]    8 MB
  bf16* qkvb  = (bf16*)(w + 31 * MB);   // [4096][3072]   24 MB
  bf16* vT    = (bf16*)(w + 55 * MB);   // [32][64][2048]  8 MB
  bf16* op0   = (bf16*)(w + 63 * MB);   // [4096][1024]    8 MB (dead after ln1)
  bf16* op1   = (bf16*)(w + 71 * MB);   //                 8 MB (aliases h1b)
  bf16* h1b   = (bf16*)(w + 71 * MB);   //                 8 MB
  bf16* ff1   = (bf16*)(w + 31 * MB);   // [4096][4096]   32 MB (reuse qkvb+vT)
  bf16* ff2p0 = (bf16*)(w + 1 * MB);    // [4096][1024]    8 MB (reuse xc)
  bf16* ff2p1 = (bf16*)(w + 63 * MB);   //                 8 MB (reuse op0)
  // peak 79 MB

  detect_dtype<<<1, 256, 0, stream>>>(x, flag);
  // fused preprocessing: convert_x + convert_small + 5 weight transposes
  prep_kernel<<<9744, 256, 0, stream>>>(x, xc,
                                        bq, bk, bv, b1, b2, g1, be1, g2, be2,
                                        sm, Wq, Wk, Wv, WqkvT,
                                        W1, W1T, W2, W2T, flag);

  // fused QKV: [4096][3072] = xc @ WqkvT^T + bqkv  (256^2 engine, 192 blocks)
  gemm_bt256<<<16 * 12, 512, 0, stream>>>(xc, WqkvT, bqkvc, qkvb,
                                          4096, 3072, 1024, 0);

  transpose_v<<<dim3(32, 2, 32), 256, 0, stream>>>(qkvb, vT);
  // split-KV attention: XCD-swizzled 1D grid (1024 blocks); partials in ln1
  attn_kernel<<<1024, 256, 0, stream>>>(qkvb, vT, op0, op1, den0, den1);

  ln1_kernel<<<4096, 256, 0, stream>>>(xc, op0, op1, den0, den1,
                                       g1c, be1c, h1b);

  // ff1: [4096][4096] = h1b @ W1T^T + b1, relu  (256^2 engine, 256 blocks)
  gemm_bt256<<<16 * 16, 512, 0, stream>>>(h1b, W1T, b1c, ff1,
                                          4096, 4096, 1024, 1);
  // ff2 split-K x2: bf16 partials, BK=64, XCD-swizzled 1D grid (1024 blocks)
  gemm_bt64_sk<<<1024, 256, 0, stream>>>(ff1, W2T, ff2p0, ff2p1,
                                         4096, 1024, 4096, 2048);

  ln2_kernel<<<4096, 256, 0, stream>>>(h1b, ff2p0, ff2p1, b2c, g2c, be2c,
                                       d_out, flag);
}

// Round 11
// 326.719 us; speedup vs baseline: 1.0051x; 1.0051x over previous
//
#include <hip/hip_runtime.h>
#include <hip/hip_bf16.h>

// TransformerEncLayer on MI355X (gfx950). B=2, M=2048, d=1024, H=16, DK=64, FF=4096.
// Tokens = 4096. LN grids = 4096.
// R25: attn QBLK 128->64 + pl-reuse (R24 post-mortem: occupancy was GRID-
//  limited -- 1024 blocks / 256 CU = 4/CU regardless of LDS; freeing LDS
//  changed nothing, occ stayed 32%). Now: grid 2048 blocks (32 qt x 16 h x
//  4 z), each wave owns ONE 16-row q-strip (no f-loop -> R24's per-f
//  serialization also gone), LDS 25.6KB -> 6 blocks/CU cap, ~24 waves/CU.
//  Cost: K/V slices read by 32 blocks (FETCH 12->24MB, XCD-local L2).
//  Tile protocol unchanged from verified R19 (stage->sync->QK->lgkm->PV->sync).
// Base: R23/R22 (gemm_bt256 interleave, verified -7us), R21 (G13 vectorized
//  LN/prep/transpose_v), R19 (fused prep), R17 (256^2 engine), R16 (BK=64
//  ff2 + swizzle), R15 (attn swizzle/XCD/setprio), R14, R13.

typedef __bf16 bf16;
typedef __attribute__((ext_vector_type(8))) __bf16 bf16x8;
typedef __attribute__((ext_vector_type(4))) __bf16 bf16x4;
typedef __attribute__((ext_vector_type(4))) float f32x4;

#define MFMA16(a, b, c) __builtin_amdgcn_mfma_f32_16x16x32_bf16(a, b, c, 0, 0, 0)

__device__ __forceinline__ void ld_g2l16(void* lds, const void* g) {
  __builtin_amdgcn_global_load_lds((const __attribute__((address_space(1))) void*)g,
                                   (__attribute__((address_space(3))) void*)lds,
                                   16, 0, 0);
}

// ---------------------------------------------------------------------------
// dtype detector (flag=1 -> fp32 inputs)
// ---------------------------------------------------------------------------
__global__ __launch_bounds__(256) void detect_dtype(const void* __restrict__ x,
                                                    int* __restrict__ flag) {
  const unsigned short* u = (const unsigned short*)x;
  int cnt = 0;
  for (int i = threadIdx.x; i < 4096; i += 256) {
    const int e = (u[i] >> 7) & 0xFF;
    if (e >= 140) ++cnt;
  }
  __shared__ int sh[256];
  sh[threadIdx.x] = cnt;
  __syncthreads();
  for (int s = 128; s > 0; s >>= 1) {
    if (threadIdx.x < s) sh[threadIdx.x] += sh[threadIdx.x + s];
    __syncthreads();
  }
  if (threadIdx.x == 0) *flag = (sh[0] > 100) ? 1 : 0;
}

__device__ __forceinline__ bf16 load_any(const void* p, size_t i, int fl) {
  return fl ? (bf16)((const float*)p)[i] : ((const bf16*)p)[i];
}

// ---------------------------------------------------------------------------
// Fused preprocessing (R21): one 1D grid, range-decoded block roles.
//  [0,4096):      convert_x (vectorized: float4 in / bf16x4 out)
//  [4096,4112):   convert_small (9 vectors -> packed sm)
//  [4112,5648):   Wq/Wk/Wv 1024^2 -> WqkvT    (64x32-in tiles, 16B stores)
//  [5648,7696):   W1 [1024][4096] -> W1T      (same scheme)
//  [7696,9744):   W2 [4096][1024] -> W2T      (same scheme)
// ---------------------------------------------------------------------------
__global__ __launch_bounds__(256) void prep_kernel(
    const void* __restrict__ x,  bf16* __restrict__ xc,
    const void* p0, const void* p1, const void* p2, const void* p3,
    const void* p4, const void* p5, const void* p6, const void* p7,
    const void* p8, bf16* __restrict__ sm,
    const void* __restrict__ Wq, const void* __restrict__ Wk,
    const void* __restrict__ Wv, bf16* __restrict__ WqkvT,
    const void* __restrict__ W1, bf16* __restrict__ W1T,
    const void* __restrict__ W2, bf16* __restrict__ W2T,
    const int* __restrict__ flag) {
  const int fl = *flag;
  const int Lb = blockIdx.x;
  const int tid = threadIdx.x;
  __shared__ bf16 t[32][72];

  if (Lb < 4096) {                       // convert_x, 1024 elems/block
    const size_t i0 = (size_t)Lb * 1024 + tid * 4;
    bf16x4 v;
    if (fl) {
      const f32x4 f = *(const f32x4*)((const float*)x + i0);
#pragma unroll
      for (int i = 0; i < 4; ++i) v[i] = (bf16)f[i];
    } else {
      v = *(const bf16x4*)((const bf16*)x + i0);
    }
    *(bf16x4*)(xc + i0) = v;
    return;
  }
  if (Lb < 4112) {                       // convert_small
    const int tt = (Lb - 4096) * 256 + tid;  // 0..4095
    const void* ps[9] = {p0, p1, p2, p3, p4, p5, p6, p7, p8};
    const int sz[9]  = {1024, 1024, 1024, 4096, 1024, 1024, 1024, 1024, 1024};
    const int off[9] = {0, 1024, 2048, 3072, 7168, 8192, 9216, 10240, 11264};
#pragma unroll
    for (int a = 0; a < 9; ++a)
      if (tt < sz[a]) sm[off[a] + tt] = load_any(ps[a], tt, fl);
    return;
  }

  // transpose sections
  const void* in;
  bf16* out;
  int R, C, r0, c0;
  if (Lb < 5648) {                       // Wq/Wk/Wv: 1024x1024 each
    const int b2 = Lb - 4112;            // 0..1535
    const int z = b2 >> 9;               // /512
    const int rem = b2 & 511;
    in = (z == 0) ? Wq : (z == 1) ? Wk : Wv;
    out = WqkvT + (size_t)z * 1024 * 1024;
    R = 1024; C = 1024;
    r0 = (rem >> 5) * 64; c0 = (rem & 31) * 32;
  } else if (Lb < 7696) {                // W1: [1024][4096]
    const int b3 = Lb - 5648;            // 0..2047
    in = W1; out = W1T; R = 1024; C = 4096;
    r0 = (b3 >> 7) * 64; c0 = (b3 & 127) * 32;
  } else {                               // W2: [4096][1024]
    const int b4 = Lb - 7696;            // 0..2047
    in = W2; out = W2T; R = 4096; C = 1024;
    r0 = (b4 >> 5) * 64; c0 = (b4 & 31) * 32;
  }
  {
    const int c = tid & 31, rr = tid >> 5;
#pragma unroll
    for (int i = 0; i < 8; ++i) {
      const int r = i * 8 + rr;
      t[c][r] = load_any(in, (size_t)(r0 + r) * C + c0 + c, fl);
    }
    __syncthreads();
    const int d = tid >> 3, ms = tid & 7;
    *(bf16x8*)&out[(size_t)(c0 + d) * R + r0 + ms * 8] = *(const bf16x8*)&t[d][ms * 8];
  }
}

// ---------------------------------------------------------------------------
// V transpose per head from fused qkvb: qkvb[4096][3072] (v at col 2048+)
// -> vT[b*16+h][64][2048]. 64m x 32d tiles, bf16x8 coalesced stores.
// ---------------------------------------------------------------------------
__global__ __launch_bounds__(256) void transpose_v(const bf16* __restrict__ qkvb,
                                                   bf16* __restrict__ vT) {
  __shared__ bf16 t[32][72];
  const int bh = blockIdx.z;
  const int b = bh >> 4, h = bh & 15;
  const int m0 = blockIdx.x * 64, d0 = blockIdx.y * 32;
  const int tid = threadIdx.x;
  const int c = tid & 31, rr = tid >> 5;
#pragma unroll
  for (int i = 0; i < 8; ++i) {
    const int m = i * 8 + rr;
    t[c][m] = qkvb[(size_t)(b * 2048 + m0 + m) * 3072 + 2048 + h * 64 + d0 + c];
  }
  __syncthreads();
  const int d = tid >> 3, ms = tid & 7;
  *(bf16x8*)&vT[((size_t)bh * 64 + d0 + d) * 2048 + m0 + ms * 8] =
      *(const bf16x8*)&t[d][ms * 8];
}

// ---------------------------------------------------------------------------
// 256x256 counted-vmcnt bt-GEMM, R22 interleaved schedule. BK=64, 8 waves.
// (unchanged from R23 -- verified)
// ---------------------------------------------------------------------------
__global__ __launch_bounds__(512, 2) void gemm_bt256(const bf16* __restrict__ A,
                                                     const bf16* __restrict__ BT,
                                                     const bf16* __restrict__ bias,
                                                     bf16* __restrict__ C,
                                                     int M, int N, int K, int relu) {
  __shared__ bf16 sA[2][256 * 64];   // 32KB per buf
  __shared__ bf16 sB[2][256 * 64];
  const int tid = threadIdx.x;
  const int w = tid >> 6, lane = tid & 63;
  const int wm = w >> 2, wn = w & 3;          // 2 x 4 wave grid
  const int m16 = lane & 15, kg = lane >> 4;
  // XCD-aware decode
  const int gx = N >> 8;
  const int L = blockIdx.x;
  const int x8 = L & 7, t1 = L >> 3;
  const int cb = t1 % gx, rb = (t1 / gx) * 8 + x8;
  const int bm = rb * 256, bn = cb * 256;
  const int strow = lane >> 3;                       // row within wave's 8
  const int sslot = ((lane & 7) ^ strow) * 8;        // swizzled source col
  const int s0 = (kg ^ (m16 & 7)) * 8;
  const int s1 = ((kg + 4) ^ (m16 & 7)) * 8;

#define STG_A(p, k0, n)                                                     \
  ld_g2l16(&sA[p][(n) * 4096 + w * 512],                                    \
           A + (size_t)(bm + (n) * 64 + w * 8 + strow) * K + (k0) + sslot)
#define STG_B(p, k0, n)                                                     \
  ld_g2l16(&sB[p][(n) * 4096 + w * 512],                                    \
           BT + (size_t)(bn + (n) * 64 + w * 8 + strow) * K + (k0) + sslot)

  f32x4 acc[8][4];
#pragma unroll
  for (int i = 0; i < 8; ++i)
#pragma unroll
    for (int j = 0; j < 4; ++j) acc[i][j] = (f32x4){0.f, 0.f, 0.f, 0.f};

  // prologue: tile 0 full (8 loads), tile 1 partial A{0,2}+B (6 loads)
  STG_A(0, 0, 0); STG_A(0, 0, 1); STG_A(0, 0, 2); STG_A(0, 0, 3);
  STG_B(0, 0, 0); STG_B(0, 0, 1); STG_B(0, 0, 2); STG_B(0, 0, 3);
  STG_A(1, 64, 0); STG_A(1, 64, 2);
  STG_B(1, 64, 0); STG_B(1, 64, 1); STG_B(1, 64, 2); STG_B(1, 64, 3);

  const int NT = K >> 6;
  for (int t = 0; t < NT; ++t) {
    const int p = t & 1;
    // leftover stage of tile t+1 (A stripes {1,3}, buf p^1): readers of those
    // regions (prev iter phase-2 frags) drained at prev iter's mid-barrier.
    if (t + 1 < NT) {
      STG_A(p ^ 1, (t + 1) * 64, 1);
      STG_A(p ^ 1, (t + 1) * 64, 3);
    }
    if (t < NT - 1)
      __asm__ __volatile__("s_waitcnt vmcnt(8)" ::: "memory");
    else
      __asm__ __volatile__("s_waitcnt vmcnt(0)" ::: "memory");
    __builtin_amdgcn_s_barrier();   // tile t fully landed, all waves

    const bf16* pA = &sA[p][(wm * 128 + m16) * 64];
    const bf16* pB = &sB[p][(wn * 64 + m16) * 64];
    bf16x8 bfr[4][2], af[4][2], af2[4][2];
#pragma unroll
    for (int nf = 0; nf < 4; ++nf) {
      bfr[nf][0] = *(const bf16x8*)(pB + nf * 1024 + s0);
      bfr[nf][1] = *(const bf16x8*)(pB + nf * 1024 + s1);
    }
#pragma unroll
    for (int mf = 0; mf < 4; ++mf) {
      af[mf][0] = *(const bf16x8*)(pA + mf * 1024 + s0);
      af[mf][1] = *(const bf16x8*)(pA + mf * 1024 + s1);
    }
    __builtin_amdgcn_sched_barrier(0);   // pin group boundary for lgkmcnt(8)
#pragma unroll
    for (int mf = 0; mf < 4; ++mf) {
      af2[mf][0] = *(const bf16x8*)(pA + (mf + 4) * 1024 + s0);
      af2[mf][1] = *(const bf16x8*)(pA + (mf + 4) * 1024 + s1);
    }
    __asm__ __volatile__("s_waitcnt lgkmcnt(8)" ::: "memory");  // first 16 done
    __builtin_amdgcn_sched_barrier(0);
    __builtin_amdgcn_s_setprio(1);
#pragma unroll
    for (int mf = 0; mf < 4; ++mf)
#pragma unroll
      for (int nf = 0; nf < 4; ++nf) {
        acc[mf][nf] = MFMA16(af[mf][0], bfr[nf][0], acc[mf][nf]);
        acc[mf][nf] = MFMA16(af[mf][1], bfr[nf][1], acc[mf][nf]);
      }
    __builtin_amdgcn_s_setprio(0);
    __asm__ __volatile__("s_waitcnt lgkmcnt(0)" ::: "memory");  // all 24 done
    __builtin_amdgcn_s_barrier();   // all waves' reads of buf p drained
    __builtin_amdgcn_sched_barrier(0);

    // stage tile t+2 (buf p): A stripes {0,2} + all B -- regions read only by
    // phase-1 frags, drained at the barrier above.
    if (t + 2 < NT) {
      const int k2 = (t + 2) * 64;
      STG_A(p, k2, 0); STG_A(p, k2, 2);
      STG_B(p, k2, 0); STG_B(p, k2, 1); STG_B(p, k2, 2); STG_B(p, k2, 3);
    }

    __builtin_amdgcn_s_setprio(1);
#pragma unroll
    for (int mf = 0; mf < 4; ++mf)
#pragma unroll
      for (int nf = 0; nf < 4; ++nf) {
        acc[mf + 4][nf] = MFMA16(af2[mf][0], bfr[nf][0], acc[mf + 4][nf]);
        acc[mf + 4][nf] = MFMA16(af2[mf][1], bfr[nf][1], acc[mf + 4][nf]);
      }
    __builtin_amdgcn_s_setprio(0);
  }
#undef STG_A
#undef STG_B

  const int r0 = bm + wm * 128, c0 = bn + wn * 64;
#pragma unroll
  for (int nf = 0; nf < 4; ++nf) {
    const int col = c0 + nf * 16 + m16;
    const float bv = (float)bias[col];
#pragma unroll
    for (int mf = 0; mf < 8; ++mf) {
#pragma unroll
      for (int r = 0; r < 4; ++r) {
        const int row = r0 + mf * 16 + kg * 4 + r;
        float v = acc[mf][nf][r] + bv;
        if (relu) v = fmaxf(v, 0.f);
        C[(size_t)row * N + col] = (bf16)v;
      }
    }
  }
}

// ---------------------------------------------------------------------------
// Split-K bt-GEMM 128x64, BK=64, XCD-swizzled 1D grid (1024 blocks).
// (R16 state -- single-buffer + __syncthreads; 24KB LDS keeps 6 blocks/CU.)
// ---------------------------------------------------------------------------
__global__ __launch_bounds__(256) void gemm_bt64_sk(const bf16* __restrict__ A,
                                                    const bf16* __restrict__ BT,
                                                    bf16* __restrict__ C0,
                                                    bf16* __restrict__ C1,
                                                    int M, int N, int Kf, int Kp) {
  __shared__ bf16 sA[2][128 * 32];   // [k-half][row][32]
  __shared__ bf16 sB[2][64 * 32];
  const int tid = threadIdx.x;
  const int wave = tid >> 6, lane = tid & 63;
  const int L = blockIdx.x;
  const int x8 = L & 7;
  const int t1 = L >> 3;
  const int cb = t1 & 15;
  const int u = t1 >> 4;
  const int z = u & 1;
  const int rb = (u >> 1) * 8 + x8;
  const int bm = rb * 128, bn = cb * 64;
  const int kbase = z * Kp;
  const int m16 = lane & 15, kg = lane >> 4;
  const int srow = lane >> 2;
  const int sswz = ((lane & 3) ^ ((srow >> 1) & 3)) * 8;
  const int kswz = (kg ^ ((m16 >> 1) & 3)) * 8;

  f32x4 acc[2][4];
#pragma unroll
  for (int i = 0; i < 2; ++i)
#pragma unroll
    for (int j = 0; j < 4; ++j) acc[i][j] = (f32x4){0.f, 0.f, 0.f, 0.f};

  for (int k0 = 0; k0 < Kp; k0 += 64) {
#pragma unroll
    for (int i = 0; i < 2; ++i) {
      const int c = wave * 2 + i;          // A row chunk 0..7
      const int row = bm + c * 16 + srow;
#pragma unroll
      for (int h = 0; h < 2; ++h)
        ld_g2l16(&sA[h][c * 512], A + (size_t)row * Kf + kbase + k0 + h * 32 + sswz);
    }
    {
      const int row = bn + wave * 16 + srow;  // B row chunk = wave
#pragma unroll
      for (int h = 0; h < 2; ++h)
        ld_g2l16(&sB[h][wave * 512], BT + (size_t)row * Kf + kbase + k0 + h * 32 + sswz);
    }
    __syncthreads();

#pragma unroll
    for (int ks = 0; ks < 2; ++ks) {
      bf16x8 af[2], bfr[4];
#pragma unroll
      for (int t = 0; t < 2; ++t)
        af[t] = *(const bf16x8*)&sA[ks][(wave * 32 + t * 16 + m16) * 32 + kswz];
#pragma unroll
      for (int t = 0; t < 4; ++t)
        bfr[t] = *(const bf16x8*)&sB[ks][(t * 16 + m16) * 32 + kswz];
#pragma unroll
      for (int mt = 0; mt < 2; ++mt)
#pragma unroll
        for (int nt = 0; nt < 4; ++nt)
          acc[mt][nt] = MFMA16(af[mt], bfr[nt], acc[mt][nt]);
    }
    __syncthreads();
  }

  bf16* C = z ? C1 : C0;
  const int r0 = bm + wave * 32;
#pragma unroll
  for (int nt = 0; nt < 4; ++nt) {
    const int col = bn + nt * 16 + m16;
#pragma unroll
    for (int mt = 0; mt < 2; ++mt) {
#pragma unroll
      for (int r = 0; r < 4; ++r) {
        const int row = r0 + mt * 16 + kg * 4 + r;
        C[(size_t)row * N + col] = (bf16)acc[mt][nt][r];
      }
    }
  }
}

// ---------------------------------------------------------------------------
// Staged flash attention, split-KV x2, QBLK=64 (R25). 1D grid, 2048 blocks.
// XCD decode: combo c=(z*16+h) in [0,64); L = (c%8) + 8*(qt + 32*(c/8)) so
// all 32 q-tiles of a combo share L%8 -> K/V slice in ONE XCD L2.
// Each wave owns one 16-row q-strip (q0 = qt*64 + wv*16); single pl buffer
// (9KB); LDS 25.6KB -> 6 blocks/CU, grid supplies 8/CU demand.
// Tile protocol = verified R19: stage -> sync -> QK -> lgkm -> PV -> sync.
// sK/sV slot-swizzle (slot ^= (row>>1)&3) source + read. exp2-domain softmax.
// Unnormalized bf16 o partials + f32 den partials; combined in ln1.
// ---------------------------------------------------------------------------
__global__ __launch_bounds__(256) void attn_kernel(const bf16* __restrict__ qkvb,
                                                   const bf16* __restrict__ vT,
                                                   bf16* __restrict__ op0,
                                                   bf16* __restrict__ op1,
                                                   float* __restrict__ den0,
                                                   float* __restrict__ den1) {
  __shared__ bf16 sK[2][64 * 32];      // 8 KB
  __shared__ bf16 sV[2][64 * 32];      // 8 KB
  __shared__ bf16 pl[4][16 * 72];      // 9 KB
  const int L = blockIdx.x;
  const int x8 = L & 7;
  const int t1 = L >> 3;
  const int qt = t1 & 31;              // 32 q-tiles of 64 rows
  const int c  = (t1 >> 5) * 8 + x8;   // combo 0..63
  const int h  = c & 15;
  const int z  = c >> 4;               // 0..3
  const int b = z >> 1, kh = z & 1;
  const int tid = threadIdx.x, wv = tid >> 6, lane = tid & 63;
  const int m16 = lane & 15, kg = lane >> 4;
  const int srow = lane >> 2;
  const int sswz = ((lane & 3) ^ ((srow >> 1) & 3)) * 8;
  const int kswz = (kg ^ ((m16 >> 1) & 3)) * 8;

  const float qs = 1.4426950408889634f / 1024.0f;
  bf16x8 fq0, fq1;
  {
    const int q0 = qt * 64 + wv * 16;
    const bf16* qp = qkvb + (size_t)(b * 2048 + q0 + m16) * 3072 + h * 64;
    bf16x8 a = *(const bf16x8*)(qp + kg * 8);
    bf16x8 cc = *(const bf16x8*)(qp + 32 + kg * 8);
#pragma unroll
    for (int i = 0; i < 8; ++i) {
      a[i] = (bf16)((float)a[i] * qs);
      cc[i] = (bf16)((float)cc[i] * qs);
    }
    fq0 = a;
    fq1 = cc;
  }

  bf16x8 ones;
#pragma unroll
  for (int i = 0; i < 8; ++i) ones[i] = (bf16)1.0f;

  f32x4 o[4], oden;
#pragma unroll
  for (int cl = 0; cl < 4; ++cl) o[cl] = (f32x4){0.f, 0.f, 0.f, 0.f};
  oden = (f32x4){0.f, 0.f, 0.f, 0.f};

  const bf16* kbase = qkvb + (size_t)(b * 2048) * 3072 + 1024 + h * 64;
  const bf16* vbase = vT + (size_t)(b * 16 + h) * 64 * 2048;
  bf16* plw = &pl[wv][0];

  const int tstart = kh * 1024;
  for (int t0 = tstart; t0 < tstart + 1024; t0 += 64) {
    {
      const int row = wv * 16 + srow;
      ld_g2l16(&sK[0][wv * 512], kbase + (size_t)(t0 + row) * 3072 + sswz);
      ld_g2l16(&sK[1][wv * 512], kbase + (size_t)(t0 + row) * 3072 + 32 + sswz);
      ld_g2l16(&sV[0][wv * 512], vbase + (size_t)row * 2048 + t0 + sswz);
      ld_g2l16(&sV[1][wv * 512], vbase + (size_t)row * 2048 + t0 + 32 + sswz);
    }
    __syncthreads();

    __builtin_amdgcn_s_setprio(1);
#pragma unroll
    for (int g = 0; g < 4; ++g) {
      const bf16x8 af0 = *(const bf16x8*)&sK[0][(g * 16 + m16) * 32 + kswz];
      const bf16x8 af1 = *(const bf16x8*)&sK[1][(g * 16 + m16) * 32 + kswz];
      f32x4 zz = (f32x4){0.f, 0.f, 0.f, 0.f};
      zz = MFMA16(af0, fq0, zz);   // S'^T[t][q], exp2 domain
      zz = MFMA16(af1, fq1, zz);
      bf16x4 pv4;
#pragma unroll
      for (int r = 0; r < 4; ++r)
        pv4[r] = (bf16)__builtin_amdgcn_exp2f(zz[r]);
      *(bf16x4*)(plw + m16 * 72 + g * 16 + kg * 4) = pv4;
    }
    __builtin_amdgcn_s_setprio(0);
    __asm__ __volatile__("s_waitcnt lgkmcnt(0)" ::: "memory");

    __builtin_amdgcn_s_setprio(1);
#pragma unroll
    for (int tt = 0; tt < 2; ++tt) {
      const bf16x8 pa = *(const bf16x8*)(plw + m16 * 72 + tt * 32 + kg * 8);
      oden = MFMA16(pa, ones, oden);
#pragma unroll
      for (int cl = 0; cl < 4; ++cl) {
        const bf16x8 fv = *(const bf16x8*)&sV[tt][(cl * 16 + m16) * 32 + kswz];
        o[cl] = MFMA16(pa, fv, o[cl]);
      }
    }
    __builtin_amdgcn_s_setprio(0);
    __syncthreads();
  }

  bf16* op = kh ? op1 : op0;
  float* dptr = kh ? den1 : den0;
#pragma unroll
  for (int r = 0; r < 4; ++r) {
    const int row = qt * 64 + wv * 16 + kg * 4 + r;
    if (m16 == 0) dptr[((b * 16 + h) << 11) + row] = oden[r];
    bf16* opp = op + (size_t)(b * 2048 + row) * 1024 + h * 64;
#pragma unroll
    for (int cl = 0; cl < 4; ++cl) opp[cl * 16 + m16] = (bf16)o[cl][r];
  }
}

// ---------------------------------------------------------------------------
// LN1 + attention combine (bf16x4 vectorized).
// attn = (op0+op1)/(den0+den1); h1b = bf16( LN(x + attn)*g1 + be1 ).
// op1 aliases h1b: reads precede the barrier, writes follow; same-thread cover.
// ---------------------------------------------------------------------------
__global__ __launch_bounds__(256) void ln1_kernel(const bf16* __restrict__ x,
                                                  const bf16* __restrict__ op0,
                                                  const bf16* __restrict__ op1,
                                                  const float* __restrict__ den0,
                                                  const float* __restrict__ den1,
                                                  const bf16* __restrict__ g,
                                                  const bf16* __restrict__ be,
                                                  bf16* __restrict__ h1b) {
  const int row = blockIdx.x;           // b*2048 + q
  const int b = row >> 11, q = row & 2047;
  const size_t base = (size_t)row * 1024;
  const int t = threadIdx.x;
  const int h = t >> 4;                 // head of this thread's 4 columns
  const float rden = 1.0f / (den0[((b * 16 + h) << 11) + q] +
                             den1[((b * 16 + h) << 11) + q]);
  const bf16x4 vo0 = *(const bf16x4*)&op0[base + t * 4];
  const bf16x4 vo1 = *(const bf16x4*)&op1[base + t * 4];
  const bf16x4 vx  = *(const bf16x4*)&x[base + t * 4];
  float v[4], s = 0.f, ss = 0.f;
#pragma unroll
  for (int i = 0; i < 4; ++i) {
    const float at = ((float)vo0[i] + (float)vo1[i]) * rden;
    const float xv = (float)vx[i] + at;
    v[i] = xv; s += xv; ss += xv * xv;
  }
#pragma unroll
  for (int m = 1; m < 64; m <<= 1) { s += __shfl_xor(s, m); ss += __shfl_xor(ss, m); }
  __shared__ float rs[4], rss[4];
  const int wave = t >> 6, lane = t & 63;
  if (lane == 0) { rs[wave] = s; rss[wave] = ss; }
  __syncthreads();
  s = rs[0] + rs[1] + rs[2] + rs[3];
  ss = rss[0] + rss[1] + rss[2] + rss[3];
  const float mu = s * (1.f / 1024.f);
  const float var = fmaxf(ss * (1.f / 1024.f) - mu * mu, 0.f);
  const float rstd = rsqrtf(var + 1e-5f);
  const bf16x4 vg  = *(const bf16x4*)&g[t * 4];
  const bf16x4 vbe = *(const bf16x4*)&be[t * 4];
  bf16x4 vout;
#pragma unroll
  for (int i = 0; i < 4; ++i)
    vout[i] = (bf16)((v[i] - mu) * rstd * (float)vg[i] + (float)vbe[i]);
  *(bf16x4*)&h1b[base + t * 4] = vout;
}

// LN2 (vectorized): out = LN(h1b + p0 + p1 + b2)*g2 + be2. grid = 4096.
__global__ __launch_bounds__(256) void ln2_kernel(const bf16* __restrict__ h1b,
                                                  const bf16* __restrict__ p0,
                                                  const bf16* __restrict__ p1,
                                                  const bf16* __restrict__ b2,
                                                  const bf16* __restrict__ g,
                                                  const bf16* __restrict__ be,
                                                  void* __restrict__ out,
                                                  const int* __restrict__ flag) {
  const int fl = *flag;
  const int row = blockIdx.x;
  const size_t base = (size_t)row * 1024;
  const int t = threadIdx.x;
  const bf16x4 vh = *(const bf16x4*)&h1b[base + t * 4];
  const bf16x4 v0 = *(const bf16x4*)&p0[base + t * 4];
  const bf16x4 v1 = *(const bf16x4*)&p1[base + t * 4];
  const bf16x4 vb2 = *(const bf16x4*)&b2[t * 4];
  float v[4], s = 0.f, ss = 0.f;
#pragma unroll
  for (int i = 0; i < 4; ++i) {
    const float xv = (float)vh[i] + (float)v0[i] + (float)v1[i] + (float)vb2[i];
    v[i] = xv; s += xv; ss += xv * xv;
  }
#pragma unroll
  for (int m = 1; m < 64; m <<= 1) { s += __shfl_xor(s, m); ss += __shfl_xor(ss, m); }
  __shared__ float rs[4], rss[4];
  const int wave = t >> 6, lane = t & 63;
  if (lane == 0) { rs[wave] = s; rss[wave] = ss; }
  __syncthreads();
  s = rs[0] + rs[1] + rs[2] + rs[3];
  ss = rss[0] + rss[1] + rss[2] + rss[3];
  const float mu = s * (1.f / 1024.f);
  const float var = fmaxf(ss * (1.f / 1024.f) - mu * mu, 0.f);
  const float rstd = rsqrtf(var + 1e-5f);
  const bf16x4 vg  = *(const bf16x4*)&g[t * 4];
  const bf16x4 vbe = *(const bf16x4*)&be[t * 4];
  if (fl) {
    f32x4 vout;
#pragma unroll
    for (int i = 0; i < 4; ++i)
      vout[i] = (v[i] - mu) * rstd * (float)vg[i] + (float)vbe[i];
    *(f32x4*)((float*)out + base + t * 4) = vout;
  } else {
    bf16x4 vout;
#pragma unroll
    for (int i = 0; i < 4; ++i)
      vout[i] = (bf16)((v[i] - mu) * rstd * (float)vg[i] + (float)vbe[i]);
    *(bf16x4*)((bf16*)out + base + t * 4) = vout;
  }
}

// ---------------------------------------------------------------------------
extern "C" void kernel_launch(void* const* d_in, const int* in_sizes, int n_in,
                              void* d_out, int out_size, void* d_ws, size_t ws_size,
                              hipStream_t stream) {
  const void* x   = d_in[0];
  const void* Wq  = d_in[2];
  const void* bq  = d_in[3];
  const void* Wk  = d_in[4];
  const void* bk  = d_in[5];
  const void* Wv  = d_in[6];
  const void* bv  = d_in[7];
  const void* W1  = d_in[8];
  const void* b1  = d_in[9];
  const void* W2  = d_in[10];
  const void* b2  = d_in[11];
  const void* g1  = d_in[12];
  const void* be1 = d_in[13];
  const void* g2  = d_in[14];
  const void* be2 = d_in[15];

  const size_t MB = 1u << 20;
  char* w = (char*)d_ws;
  int*  flag = (int*)w;                       // 4 B
  bf16* sm   = (bf16*)(w + 65536);            // packed small vectors (~24 KB)
  bf16* bqkvc = sm + 0;        // 3072
  bf16* b1c   = sm + 3072;     // 4096
  bf16* b2c   = sm + 7168;     // 1024
  bf16* g1c   = sm + 8192;
  bf16* be1c  = sm + 9216;
  bf16* g2c   = sm + 10240;
  bf16* be2c  = sm + 11264;
  float* den0 = (float*)(w + 512 * 1024);   // [32][2048] f32 256 KB
  float* den1 = (float*)(w + 768 * 1024);   //            256 KB
  bf16* xc    = (bf16*)(w + 1 * MB);    // [4096][1024]    8 MB (dead after ln1)
  bf16* WqkvT = (bf16*)(w + 9 * MB);    // [3072][1024]    6 MB
  bf16* W1T   = (bf16*)(w + 15 * MB);   // [4096][1024]    8 MB
  bf16* W2T   = (bf16*)(w + 23 * MB);   // [1024][4096]    8 MB
  bf16* qkvb  = (bf16*)(w + 31 * MB);   // [4096][3072]   24 MB
  bf16* vT    = (bf16*)(w + 55 * MB);   // [32][64][2048]  8 MB
  bf16* op0   = (bf16*)(w + 63 * MB);   // [4096][1024]    8 MB (dead after ln1)
  bf16* op1   = (bf16*)(w + 71 * MB);   //                 8 MB (aliases h1b)
  bf16* h1b   = (bf16*)(w + 71 * MB);   //                 8 MB
  bf16* ff1   = (bf16*)(w + 31 * MB);   // [4096][4096]   32 MB (reuse qkvb+vT)
  bf16* ff2p0 = (bf16*)(w + 1 * MB);    // [4096][1024]    8 MB (reuse xc)
  bf16* ff2p1 = (bf16*)(w + 63 * MB);   //                 8 MB (reuse op0)
  // peak 79 MB

  detect_dtype<<<1, 256, 0, stream>>>(x, flag);
  // fused preprocessing: convert_x + convert_small + 5 weight transposes
  prep_kernel<<<9744, 256, 0, stream>>>(x, xc,
                                        bq, bk, bv, b1, b2, g1, be1, g2, be2,
                                        sm, Wq, Wk, Wv, WqkvT,
                                        W1, W1T, W2, W2T, flag);

  // fused QKV: [4096][3072] = xc @ WqkvT^T + bqkv  (256^2 engine, 192 blocks)
  gemm_bt256<<<16 * 12, 512, 0, stream>>>(xc, WqkvT, bqkvc, qkvb,
                                          4096, 3072, 1024, 0);

  transpose_v<<<dim3(32, 2, 32), 256, 0, stream>>>(qkvb, vT);
  // split-KV attention: QBLK=64, XCD-swizzled 1D grid (2048 blocks)
  attn_kernel<<<2048, 256, 0, stream>>>(qkvb, vT, op0, op1, den0, den1);

  ln1_kernel<<<4096, 256, 0, stream>>>(xc, op0, op1, den0, den1,
                                       g1c, be1c, h1b);

  // ff1: [4096][4096] = h1b @ W1T^T + b1, relu  (256^2 engine, 256 blocks)
  gemm_bt256<<<16 * 16, 512, 0, stream>>>(h1b, W1T, b1c, ff1,
                                          4096, 4096, 1024, 1);
  // ff2 split-K x2: bf16 partials, BK=64, XCD-swizzled 1D grid (1024 blocks)
  gemm_bt64_sk<<<1024, 256, 0, stream>>>(ff1, W2T, ff2p0, ff2p1,
                                         4096, 1024, 4096, 2048);

  ln2_kernel<<<4096, 256, 0, stream>>>(h1b, ff2p0, ff2p1, b2c, g2c, be2c,
                                       d_out, flag);
}